// Round 15
// baseline (24.648 us; speedup 1.0000x reference)
//
#include <hip/hip_runtime.h>

#define TLEN  200
#define H1    128
#define H2    64

typedef __attribute__((ext_vector_type(8))) short bf16x8;
typedef __attribute__((ext_vector_type(4))) float f32x4;

union Frag { unsigned u[4]; bf16x8 v; };

// pack two fp32 into (hi-pair, lo-pair) of bf16 bits: hi = truncate, lo = residual
__device__ __forceinline__ void split2(float v0, float v1, unsigned& hi, unsigned& lo) {
    const unsigned u0 = __float_as_uint(v0), u1 = __float_as_uint(v1);
    hi = __builtin_amdgcn_perm(u1, u0, 0x07060302);          // {u1.hi16, u0.hi16}
    const float d0 = v0 - __uint_as_float(u0 & 0xFFFF0000u);
    const float d1 = v1 - __uint_as_float(u1 & 0xFFFF0000u);
    lo = __builtin_amdgcn_perm(__float_as_uint(d1), __float_as_uint(d0), 0x07060302);
}

// bit-sliced accumulator += a + b (two one-hot u32), 6 planes
__device__ __forceinline__ void csa_add(uint32_t p[6], uint32_t a, uint32_t b) {
    const uint32_t t = a ^ b;
    uint32_t c = (a & b) | (p[0] & t);
    p[0] ^= t;
    uint32_t cn;
    cn = p[1] & c; p[1] ^= c; c = cn;
    cn = p[2] & c; p[2] ^= c; c = cn;
    cn = p[3] & c; p[3] ^= c; c = cn;
    cn = p[4] & c; p[4] ^= c; c = cn;
    p[5] ^= c;
}

// 64 samples/block, 4 waves, LDS 34816 B. R15 = R14 (best, 24.14us) with the
// cold-start cover extended to depth 2: q0 AND q1 issued before the W-convert
// (+8 VGPR across convert — half of R6's failure threshold, no index reshuffle).
// R9 proved in-loop depth is TLP-covered; only the loop-entry misses are exposed.
__global__ __launch_bounds__(256, 4)
void gating_fused(const int* __restrict__ x,
                  const float* __restrict__ W1, const float* __restrict__ b1,
                  const float* __restrict__ W2, const float* __restrict__ b2,
                  const float* __restrict__ W3, const float* __restrict__ b3,
                  float* __restrict__ out)
{
    // overlay plan (34816 B):
    //   phase A (hist -> L1):  feath[64][72] u16 @ 0          (9216 B)
    //   phase B (L1 -> L2):    h1hi[64][136] @ 0, h1lo @ 17408
    //   phase C (L2 -> L3):    h2s[64][67] f32 @ 0            (17152 B)
    //   phase D (L3 -> end):   lbuf stride-5 f32 @ 17408      (5120 B)
    __shared__ __align__(16) unsigned char raw[34816];
    unsigned short (*feath)[72] = (unsigned short (*)[72])raw;
    unsigned short (*h1hi)[136] = (unsigned short (*)[136])raw;
    unsigned short (*h1lo)[136] = (unsigned short (*)[136])(raw + 17408);
    float* h2s  = (float*)raw;
    float* lbuf = (float*)(raw + 17408);      // [(w*64+lane)*5 + e]

    const int tid  = threadIdx.x;
    const int lane = tid & 63;
    const int w    = __builtin_amdgcn_readfirstlane(tid >> 6);
    const int r    = lane & 15;
    const int g    = lane >> 4;

    // ---------- first TWO x chunks in flight before W-convert -------------------
    const int sub   = tid & 3;
    const int s_loc = tid >> 2;
    const long srow = (long)blockIdx.x * 64 + s_loc;
    const int4* xr = (const int4*)(x + srow * TLEN);
    const int nm = (sub < 2) ? 13 : 12;
    int4 q0 = xr[sub];                        // +8 VGPR live across convert
    int4 q1 = xr[sub + 4];

    // ---------- W fragments in registers (trunc hi + residual lo bf16) ----------
    Frag w1h[2][2], w1l[2][2], w2h[4], w2l[4];
    #pragma unroll
    for (int n = 0; n < 2; ++n)
        #pragma unroll
        for (int s = 0; s < 2; ++s) {
            const int col = w * 32 + n * 16 + r;
            #pragma unroll
            for (int j = 0; j < 4; ++j) {
                const int k = s * 32 + g * 8 + j * 2;
                const float v0 = (k     < 42) ? W1[k * H1 + col]       : 0.0f;
                const float v1 = (k + 1 < 42) ? W1[(k + 1) * H1 + col] : 0.0f;
                split2(v0, v1, w1h[n][s].u[j], w1l[n][s].u[j]);
            }
        }
    #pragma unroll
    for (int s = 0; s < 4; ++s) {
        const int col = w * 16 + r;
        #pragma unroll
        for (int j = 0; j < 4; ++j) {
            const int k = s * 32 + g * 8 + j * 2;
            split2(W2[k * H2 + col], W2[(k + 1) * H2 + col], w2h[s].u[j], w2l[s].u[j]);
        }
    }
    float b1v[2];
    b1v[0] = b1[w * 32 + r];
    b1v[1] = b1[w * 32 + 16 + r];
    const float b2v = b2[w * 16 + r];

    // ================= histogram: 4 subs/sample, depth-2 pipelined ==============
    uint32_t plo[6] = {0,0,0,0,0,0}, phi[6] = {0,0,0,0,0,0};

    for (int m = 0; m < nm; ++m) {
        const int pidx = m + 2;
        const int nidx = (pidx < nm) ? (sub + 4 * pidx) : sub;
        const int4 nxt = xr[nidx];            // keep 2 loads in flight
        {   // pad token 0 lands in plane bit 0 -> never extracted (bin 0 skipped)
            const uint64_t oa = 1ull << (q0.x & 63);
            const uint64_t ob = 1ull << (q0.y & 63);
            csa_add(plo, (uint32_t)oa, (uint32_t)ob);
            csa_add(phi, (uint32_t)(oa >> 32), (uint32_t)(ob >> 32));
        }
        {
            const uint64_t oa = 1ull << (q0.z & 63);
            const uint64_t ob = 1ull << (q0.w & 63);
            csa_add(plo, (uint32_t)oa, (uint32_t)ob);
            csa_add(phi, (uint32_t)(oa >> 32), (uint32_t)(ob >> 32));
        }
        q0 = q1; q1 = nxt;
    }

    // ---- merge planes across the 4 subs (bit-sliced vector adds via shfl) ----
    uint32_t alo[8], ahi[8];
    {
        uint32_t c = 0;
        #pragma unroll
        for (int p = 0; p < 6; ++p) {
            const uint32_t q = __shfl_xor(plo[p], 1);
            const uint32_t t = plo[p] ^ q;
            alo[p] = t ^ c;
            c = (plo[p] & q) | (t & c);
        }
        alo[6] = c;
        c = 0;
        #pragma unroll
        for (int p = 0; p < 6; ++p) {
            const uint32_t q = __shfl_xor(phi[p], 1);
            const uint32_t t = phi[p] ^ q;
            ahi[p] = t ^ c;
            c = (phi[p] & q) | (t & c);
        }
        ahi[6] = c;
        c = 0;
        #pragma unroll
        for (int p = 0; p < 7; ++p) {
            const uint32_t q = __shfl_xor(alo[p], 2);
            const uint32_t t = alo[p] ^ q;
            const uint32_t cn = (alo[p] & q) | (t & c);
            alo[p] = t ^ c;
            c = cn;
        }
        alo[7] = c;
        c = 0;
        #pragma unroll
        for (int p = 0; p < 7; ++p) {
            const uint32_t q = __shfl_xor(ahi[p], 2);
            const uint32_t t = ahi[p] ^ q;
            const uint32_t cn = (ahi[p] & q) | (t & c);
            ahi[p] = t ^ c;
            c = cn;
        }
        ahi[7] = c;
    }

    // ---- extraction: sub s owns a bin slice; bins 1..11 / 12..21 / 22..31 / 32..39
    uint32_t P[8];
    #pragma unroll
    for (int p = 0; p < 8; ++p) P[p] = (sub == 3) ? ahi[p] : alo[p];
    const int nb   = (sub == 0) ? 11 : (sub == 3) ? 8 : 10;
    const int base = (sub == 0) ? 1 : (sub == 1) ? 12 : (sub == 2) ? 22 : 0;
    const int coff = (sub == 3) ? 32 : 0;

    uint32_t tot = 0u, unq = 0u;
    for (int j = 0; j < 11; ++j) {
        if (j < nb) {
            const int sh = base + j;
            uint32_t cnt = 0u;
            #pragma unroll
            for (int p = 0; p < 8; ++p) cnt += ((P[p] >> sh) & 1u) << p;
            tot += cnt;
            unq += (cnt != 0u) ? 1u : 0u;
            feath[s_loc][2 + sh + coff] =
                (unsigned short)(__float_as_uint((float)cnt) >> 16);  // exact int->bf16
        }
    }
    tot += __shfl_xor(tot, 1); tot += __shfl_xor(tot, 2);
    unq += __shfl_xor(unq, 1); unq += __shfl_xor(unq, 2);

    uint32_t* rw = (uint32_t*)&feath[s_loc][0];
    if (sub == 0)
        rw[0] = (__float_as_uint((float)tot) >> 16)
              | ((__float_as_uint((float)unq) >> 16) << 16);      // f[0], f[1]
    if (sub == 1) feath[s_loc][2] = 0;                            // char_freq[0] = 0
    #pragma unroll
    for (int rep = 0; rep < 3; ++rep) {                           // zero k = 42..63
        const int wz = 21 + rep * 4 + sub;
        if (wz <= 31) rw[wz] = 0u;
    }
    __syncthreads();                                              // B1: feat ready

    // ================= layer1: C1[64x128] = feat[64x64] @ W1 ====================
    f32x4 acc1[4][2];
    #pragma unroll
    for (int m = 0; m < 4; ++m)
        #pragma unroll
        for (int n = 0; n < 2; ++n)
            acc1[m][n] = (f32x4){b1v[n], b1v[n], b1v[n], b1v[n]};

    __builtin_amdgcn_s_setprio(1);
    #pragma unroll
    for (int s = 0; s < 2; ++s)
        #pragma unroll
        for (int m = 0; m < 4; ++m) {
            const bf16x8 af = *(const bf16x8*)&feath[m * 16 + r][s * 32 + g * 8];
            #pragma unroll
            for (int n = 0; n < 2; ++n) {
                acc1[m][n] = __builtin_amdgcn_mfma_f32_16x16x32_bf16(af, w1h[n][s].v, acc1[m][n], 0, 0, 0);
                acc1[m][n] = __builtin_amdgcn_mfma_f32_16x16x32_bf16(af, w1l[n][s].v, acc1[m][n], 0, 0, 0);
            }
        }
    __builtin_amdgcn_s_setprio(0);
    __syncthreads();                          // B2: feath reads done (h1 overlays it)

    // relu + trunc hi/lo split -> LDS (C/D: col=lane&15, row=(lane>>4)*4+reg)
    #pragma unroll
    for (int m = 0; m < 4; ++m)
        #pragma unroll
        for (int n = 0; n < 2; ++n)
            #pragma unroll
            for (int j = 0; j < 4; ++j) {
                const float hv = fmaxf(acc1[m][n][j], 0.0f);
                const unsigned ub = __float_as_uint(hv);
                const float d = hv - __uint_as_float(ub & 0xFFFF0000u);
                const int row = m * 16 + g * 4 + j;
                const int col = w * 32 + n * 16 + r;
                h1hi[row][col] = (unsigned short)(ub >> 16);
                h1lo[row][col] = (unsigned short)(__float_as_uint(d) >> 16);
            }
    __syncthreads();                          // B3: h1 ready

    // ================= layer2: C2[64x64] = h1[64x128] @ W2, 3-pass hi/lo ========
    f32x4 acc2[4];
    #pragma unroll
    for (int m = 0; m < 4; ++m) acc2[m] = (f32x4){b2v, b2v, b2v, b2v};

    __builtin_amdgcn_s_setprio(1);
    #pragma unroll
    for (int s = 0; s < 4; ++s)
        #pragma unroll
        for (int m = 0; m < 4; ++m) {
            const int row = m * 16 + r;
            const int kh  = s * 32 + g * 8;
            const bf16x8 ah = *(const bf16x8*)&h1hi[row][kh];
            const bf16x8 al = *(const bf16x8*)&h1lo[row][kh];
            acc2[m] = __builtin_amdgcn_mfma_f32_16x16x32_bf16(ah, w2h[s].v, acc2[m], 0, 0, 0);
            acc2[m] = __builtin_amdgcn_mfma_f32_16x16x32_bf16(al, w2h[s].v, acc2[m], 0, 0, 0);
            acc2[m] = __builtin_amdgcn_mfma_f32_16x16x32_bf16(ah, w2l[s].v, acc2[m], 0, 0, 0);
        }
    __builtin_amdgcn_s_setprio(0);
    __syncthreads();                          // B4: h1 reads done (h2s overlays h1hi)

    // relu(h2) -> fp32 LDS (stride 67 words: conflict-free column gather)
    #pragma unroll
    for (int m = 0; m < 4; ++m)
        #pragma unroll
        for (int j = 0; j < 4; ++j) {
            const int row = m * 16 + g * 4 + j;
            h2s[row * 67 + w * 16 + r] = fmaxf(acc2[m][j], 0.0f);
        }
    // NO barrier (was B5): wave w wrote exactly the h2s columns [w*16, w*16+16)
    // it reads below; within-wave lgkmcnt ordering suffices (R11-verified).

    // ================= layer3 partials: sample per lane, K-split by wave ========
    float lg0 = 0.f, lg1 = 0.f, lg2 = 0.f;
    for (int kk = 0; kk < 16; ++kk) {
        const float hv = h2s[lane * 67 + w * 16 + kk];
        const int wr = (w * 16 + kk) * 3;
        lg0 = fmaf(hv, W3[wr + 0], lg0);
        lg1 = fmaf(hv, W3[wr + 1], lg1);
        lg2 = fmaf(hv, W3[wr + 2], lg2);
    }
    lbuf[(w * 64 + lane) * 5 + 0] = lg0;      // stride 5: gcd(5,32)=1, conflict-free
    lbuf[(w * 64 + lane) * 5 + 1] = lg1;
    lbuf[(w * 64 + lane) * 5 + 2] = lg2;
    __syncthreads();                          // B6: partials ready (cross-wave)

    // ================= reduce, softmax, store ===================================
    float l0 = b3[0], l1 = b3[1], l2 = b3[2];
    #pragma unroll
    for (int wq = 0; wq < 4; ++wq) {
        l0 += lbuf[(wq * 64 + lane) * 5 + 0];
        l1 += lbuf[(wq * 64 + lane) * 5 + 1];
        l2 += lbuf[(wq * 64 + lane) * 5 + 2];
    }
    const float mx  = fmaxf(l0, fmaxf(l1, l2));
    const float e0  = __expf(l0 - mx), e1 = __expf(l1 - mx), e2 = __expf(l2 - mx);
    const float inv = 1.0f / (e0 + e1 + e2);
    if (w < 3) {
        const long gs = (long)blockIdx.x * 64 + lane;
        const float v = (w == 0) ? e0 * inv : (w == 1) ? e1 * inv : e2 * inv;
        out[gs * 3 + w] = v;
    }
}

extern "C" void kernel_launch(void* const* d_in, const int* in_sizes, int n_in,
                              void* d_out, int out_size, void* d_ws, size_t ws_size,
                              hipStream_t stream) {
    const int*   x  = (const int*)d_in[0];
    const float* W1 = (const float*)d_in[1];
    const float* b1 = (const float*)d_in[2];
    const float* W2 = (const float*)d_in[3];
    const float* b2 = (const float*)d_in[4];
    const float* W3 = (const float*)d_in[5];
    const float* b3 = (const float*)d_in[6];
    float* out = (float*)d_out;

    const int B = in_sizes[0] / TLEN;   // 65536
    gating_fused<<<B / 64, 256, 0, stream>>>(x, W1, b1, W2, b2, W3, b3, out);
}

// Round 16
// 24.269 us; speedup vs baseline: 1.0156x; 1.0156x over previous
//
#include <hip/hip_runtime.h>

#define TLEN  200
#define H1    128
#define H2    64

typedef __attribute__((ext_vector_type(8))) short bf16x8;
typedef __attribute__((ext_vector_type(4))) float f32x4;

union Frag { unsigned u[4]; bf16x8 v; };

// pack two fp32 into (hi-pair, lo-pair) of bf16 bits: hi = truncate, lo = residual
__device__ __forceinline__ void split2(float v0, float v1, unsigned& hi, unsigned& lo) {
    const unsigned u0 = __float_as_uint(v0), u1 = __float_as_uint(v1);
    hi = __builtin_amdgcn_perm(u1, u0, 0x07060302);          // {u1.hi16, u0.hi16}
    const float d0 = v0 - __uint_as_float(u0 & 0xFFFF0000u);
    const float d1 = v1 - __uint_as_float(u1 & 0xFFFF0000u);
    lo = __builtin_amdgcn_perm(__float_as_uint(d1), __float_as_uint(d0), 0x07060302);
}

// bit-sliced accumulator += a + b (two one-hot u32), 6 planes
__device__ __forceinline__ void csa_add(uint32_t p[6], uint32_t a, uint32_t b) {
    const uint32_t t = a ^ b;
    uint32_t c = (a & b) | (p[0] & t);
    p[0] ^= t;
    uint32_t cn;
    cn = p[1] & c; p[1] ^= c; c = cn;
    cn = p[2] & c; p[2] ^= c; c = cn;
    cn = p[3] & c; p[3] ^= c; c = cn;
    cn = p[4] & c; p[4] ^= c; c = cn;
    p[5] ^= c;
}

// FINAL (R14, session best: 24.14us). 64 samples/block, 4 waves, LDS 34816 B.
// Structure: register bitplane histogram (4 subs/sample, CSA one-hot adds,
// shfl merge) -> bf16 features -> MFMA 16x16x32 MLP with hi/lo precision
// splits -> fused softmax. First x chunk issued before the W-convert section
// (cold-start miss hides under ~250 convert instructions; +4 VGPR only).
// Measured constraint: MLP needs ~84 VGPR (>64-VGPR occupancy cliff) -> fixed
// 4 waves/SIMD; kernel is latency-bound at ~60-65% VALU issue. Probes below
// 64 VGPR (R8, R12) and kernel splits (R10) all regressed.
__global__ __launch_bounds__(256, 4)
void gating_fused(const int* __restrict__ x,
                  const float* __restrict__ W1, const float* __restrict__ b1,
                  const float* __restrict__ W2, const float* __restrict__ b2,
                  const float* __restrict__ W3, const float* __restrict__ b3,
                  float* __restrict__ out)
{
    // overlay plan (34816 B):
    //   phase A (hist -> L1):  feath[64][72] u16 @ 0          (9216 B)
    //   phase B (L1 -> L2):    h1hi[64][136] @ 0, h1lo @ 17408
    //   phase C (L2 -> L3):    h2s[64][67] f32 @ 0            (17152 B)
    //   phase D (L3 -> end):   lbuf stride-5 f32 @ 17408      (5120 B)
    __shared__ __align__(16) unsigned char raw[34816];
    unsigned short (*feath)[72] = (unsigned short (*)[72])raw;
    unsigned short (*h1hi)[136] = (unsigned short (*)[136])raw;
    unsigned short (*h1lo)[136] = (unsigned short (*)[136])(raw + 17408);
    float* h2s  = (float*)raw;
    float* lbuf = (float*)(raw + 17408);      // [(w*64+lane)*5 + e]

    const int tid  = threadIdx.x;
    const int lane = tid & 63;
    const int w    = __builtin_amdgcn_readfirstlane(tid >> 6);
    const int r    = lane & 15;
    const int g    = lane >> 4;

    // ---------- FIRST x chunk in flight before W-convert (cold-start cover) -----
    const int sub   = tid & 3;
    const int s_loc = tid >> 2;
    const long srow = (long)blockIdx.x * 64 + s_loc;
    const int4* xr = (const int4*)(x + srow * TLEN);
    const int nm = (sub < 2) ? 13 : 12;
    int4 cur = xr[sub];                       // +4 VGPR live across convert

    // ---------- W fragments in registers (trunc hi + residual lo bf16) ----------
    Frag w1h[2][2], w1l[2][2], w2h[4], w2l[4];
    #pragma unroll
    for (int n = 0; n < 2; ++n)
        #pragma unroll
        for (int s = 0; s < 2; ++s) {
            const int col = w * 32 + n * 16 + r;
            #pragma unroll
            for (int j = 0; j < 4; ++j) {
                const int k = s * 32 + g * 8 + j * 2;
                const float v0 = (k     < 42) ? W1[k * H1 + col]       : 0.0f;
                const float v1 = (k + 1 < 42) ? W1[(k + 1) * H1 + col] : 0.0f;
                split2(v0, v1, w1h[n][s].u[j], w1l[n][s].u[j]);
            }
        }
    #pragma unroll
    for (int s = 0; s < 4; ++s) {
        const int col = w * 16 + r;
        #pragma unroll
        for (int j = 0; j < 4; ++j) {
            const int k = s * 32 + g * 8 + j * 2;
            split2(W2[k * H2 + col], W2[(k + 1) * H2 + col], w2h[s].u[j], w2l[s].u[j]);
        }
    }
    float b1v[2];
    b1v[0] = b1[w * 32 + r];
    b1v[1] = b1[w * 32 + 16 + r];
    const float b2v = b2[w * 16 + r];

    // ================= histogram: 4 subs/sample, 1-instr one-hot + pair CSA =====
    uint32_t plo[6] = {0,0,0,0,0,0}, phi[6] = {0,0,0,0,0,0};

    for (int m = 0; m < nm; ++m) {
        const int nidx = (m + 1 < nm) ? (sub + 4 * (m + 1)) : sub;
        const int4 nxt = xr[nidx];            // one load in flight during processing
        {   // pad token 0 lands in plane bit 0 -> never extracted (bin 0 skipped)
            const uint64_t oa = 1ull << (cur.x & 63);
            const uint64_t ob = 1ull << (cur.y & 63);
            csa_add(plo, (uint32_t)oa, (uint32_t)ob);
            csa_add(phi, (uint32_t)(oa >> 32), (uint32_t)(ob >> 32));
        }
        {
            const uint64_t oa = 1ull << (cur.z & 63);
            const uint64_t ob = 1ull << (cur.w & 63);
            csa_add(plo, (uint32_t)oa, (uint32_t)ob);
            csa_add(phi, (uint32_t)(oa >> 32), (uint32_t)(ob >> 32));
        }
        cur = nxt;
    }

    // ---- merge planes across the 4 subs (bit-sliced vector adds via shfl) ----
    uint32_t alo[8], ahi[8];
    {
        uint32_t c = 0;
        #pragma unroll
        for (int p = 0; p < 6; ++p) {
            const uint32_t q = __shfl_xor(plo[p], 1);
            const uint32_t t = plo[p] ^ q;
            alo[p] = t ^ c;
            c = (plo[p] & q) | (t & c);
        }
        alo[6] = c;
        c = 0;
        #pragma unroll
        for (int p = 0; p < 6; ++p) {
            const uint32_t q = __shfl_xor(phi[p], 1);
            const uint32_t t = phi[p] ^ q;
            ahi[p] = t ^ c;
            c = (phi[p] & q) | (t & c);
        }
        ahi[6] = c;
        c = 0;
        #pragma unroll
        for (int p = 0; p < 7; ++p) {
            const uint32_t q = __shfl_xor(alo[p], 2);
            const uint32_t t = alo[p] ^ q;
            const uint32_t cn = (alo[p] & q) | (t & c);
            alo[p] = t ^ c;
            c = cn;
        }
        alo[7] = c;
        c = 0;
        #pragma unroll
        for (int p = 0; p < 7; ++p) {
            const uint32_t q = __shfl_xor(ahi[p], 2);
            const uint32_t t = ahi[p] ^ q;
            const uint32_t cn = (ahi[p] & q) | (t & c);
            ahi[p] = t ^ c;
            c = cn;
        }
        ahi[7] = c;
    }

    // ---- extraction: sub s owns a bin slice; bins 1..11 / 12..21 / 22..31 / 32..39
    uint32_t P[8];
    #pragma unroll
    for (int p = 0; p < 8; ++p) P[p] = (sub == 3) ? ahi[p] : alo[p];
    const int nb   = (sub == 0) ? 11 : (sub == 3) ? 8 : 10;
    const int base = (sub == 0) ? 1 : (sub == 1) ? 12 : (sub == 2) ? 22 : 0;
    const int coff = (sub == 3) ? 32 : 0;

    uint32_t tot = 0u, unq = 0u;
    for (int j = 0; j < 11; ++j) {
        if (j < nb) {
            const int sh = base + j;
            uint32_t cnt = 0u;
            #pragma unroll
            for (int p = 0; p < 8; ++p) cnt += ((P[p] >> sh) & 1u) << p;
            tot += cnt;
            unq += (cnt != 0u) ? 1u : 0u;
            feath[s_loc][2 + sh + coff] =
                (unsigned short)(__float_as_uint((float)cnt) >> 16);  // exact int->bf16
        }
    }
    tot += __shfl_xor(tot, 1); tot += __shfl_xor(tot, 2);
    unq += __shfl_xor(unq, 1); unq += __shfl_xor(unq, 2);

    uint32_t* rw = (uint32_t*)&feath[s_loc][0];
    if (sub == 0)
        rw[0] = (__float_as_uint((float)tot) >> 16)
              | ((__float_as_uint((float)unq) >> 16) << 16);      // f[0], f[1]
    if (sub == 1) feath[s_loc][2] = 0;                            // char_freq[0] = 0
    #pragma unroll
    for (int rep = 0; rep < 3; ++rep) {                           // zero k = 42..63
        const int wz = 21 + rep * 4 + sub;
        if (wz <= 31) rw[wz] = 0u;
    }
    __syncthreads();                                              // B1: feat ready

    // ================= layer1: C1[64x128] = feat[64x64] @ W1 ====================
    f32x4 acc1[4][2];
    #pragma unroll
    for (int m = 0; m < 4; ++m)
        #pragma unroll
        for (int n = 0; n < 2; ++n)
            acc1[m][n] = (f32x4){b1v[n], b1v[n], b1v[n], b1v[n]};

    __builtin_amdgcn_s_setprio(1);
    #pragma unroll
    for (int s = 0; s < 2; ++s)
        #pragma unroll
        for (int m = 0; m < 4; ++m) {
            const bf16x8 af = *(const bf16x8*)&feath[m * 16 + r][s * 32 + g * 8];
            #pragma unroll
            for (int n = 0; n < 2; ++n) {
                acc1[m][n] = __builtin_amdgcn_mfma_f32_16x16x32_bf16(af, w1h[n][s].v, acc1[m][n], 0, 0, 0);
                acc1[m][n] = __builtin_amdgcn_mfma_f32_16x16x32_bf16(af, w1l[n][s].v, acc1[m][n], 0, 0, 0);
            }
        }
    __builtin_amdgcn_s_setprio(0);
    __syncthreads();                          // B2: feath reads done (h1 overlays it)

    // relu + trunc hi/lo split -> LDS (C/D: col=lane&15, row=(lane>>4)*4+reg)
    #pragma unroll
    for (int m = 0; m < 4; ++m)
        #pragma unroll
        for (int n = 0; n < 2; ++n)
            #pragma unroll
            for (int j = 0; j < 4; ++j) {
                const float hv = fmaxf(acc1[m][n][j], 0.0f);
                const unsigned ub = __float_as_uint(hv);
                const float d = hv - __uint_as_float(ub & 0xFFFF0000u);
                const int row = m * 16 + g * 4 + j;
                const int col = w * 32 + n * 16 + r;
                h1hi[row][col] = (unsigned short)(ub >> 16);
                h1lo[row][col] = (unsigned short)(__float_as_uint(d) >> 16);
            }
    __syncthreads();                          // B3: h1 ready

    // ================= layer2: C2[64x64] = h1[64x128] @ W2, 3-pass hi/lo ========
    f32x4 acc2[4];
    #pragma unroll
    for (int m = 0; m < 4; ++m) acc2[m] = (f32x4){b2v, b2v, b2v, b2v};

    __builtin_amdgcn_s_setprio(1);
    #pragma unroll
    for (int s = 0; s < 4; ++s)
        #pragma unroll
        for (int m = 0; m < 4; ++m) {
            const int row = m * 16 + r;
            const int kh  = s * 32 + g * 8;
            const bf16x8 ah = *(const bf16x8*)&h1hi[row][kh];
            const bf16x8 al = *(const bf16x8*)&h1lo[row][kh];
            acc2[m] = __builtin_amdgcn_mfma_f32_16x16x32_bf16(ah, w2h[s].v, acc2[m], 0, 0, 0);
            acc2[m] = __builtin_amdgcn_mfma_f32_16x16x32_bf16(al, w2h[s].v, acc2[m], 0, 0, 0);
            acc2[m] = __builtin_amdgcn_mfma_f32_16x16x32_bf16(ah, w2l[s].v, acc2[m], 0, 0, 0);
        }
    __builtin_amdgcn_s_setprio(0);
    __syncthreads();                          // B4: h1 reads done (h2s overlays h1hi)

    // relu(h2) -> fp32 LDS (stride 67 words: conflict-free column gather)
    #pragma unroll
    for (int m = 0; m < 4; ++m)
        #pragma unroll
        for (int j = 0; j < 4; ++j) {
            const int row = m * 16 + g * 4 + j;
            h2s[row * 67 + w * 16 + r] = fmaxf(acc2[m][j], 0.0f);
        }
    // NO barrier (was B5): wave w wrote exactly the h2s columns [w*16, w*16+16)
    // it reads below; within-wave lgkmcnt ordering suffices (R11-verified).

    // ================= layer3 partials: sample per lane, K-split by wave ========
    float lg0 = 0.f, lg1 = 0.f, lg2 = 0.f;
    for (int kk = 0; kk < 16; ++kk) {
        const float hv = h2s[lane * 67 + w * 16 + kk];
        const int wr = (w * 16 + kk) * 3;
        lg0 = fmaf(hv, W3[wr + 0], lg0);
        lg1 = fmaf(hv, W3[wr + 1], lg1);
        lg2 = fmaf(hv, W3[wr + 2], lg2);
    }
    lbuf[(w * 64 + lane) * 5 + 0] = lg0;      // stride 5: gcd(5,32)=1, conflict-free
    lbuf[(w * 64 + lane) * 5 + 1] = lg1;
    lbuf[(w * 64 + lane) * 5 + 2] = lg2;
    __syncthreads();                          // B6: partials ready (cross-wave)

    // ================= reduce, softmax, store ===================================
    float l0 = b3[0], l1 = b3[1], l2 = b3[2];
    #pragma unroll
    for (int wq = 0; wq < 4; ++wq) {
        l0 += lbuf[(wq * 64 + lane) * 5 + 0];
        l1 += lbuf[(wq * 64 + lane) * 5 + 1];
        l2 += lbuf[(wq * 64 + lane) * 5 + 2];
    }
    const float mx  = fmaxf(l0, fmaxf(l1, l2));
    const float e0  = __expf(l0 - mx), e1 = __expf(l1 - mx), e2 = __expf(l2 - mx);
    const float inv = 1.0f / (e0 + e1 + e2);
    if (w < 3) {
        const long gs = (long)blockIdx.x * 64 + lane;
        const float v = (w == 0) ? e0 * inv : (w == 1) ? e1 * inv : e2 * inv;
        out[gs * 3 + w] = v;
    }
}

extern "C" void kernel_launch(void* const* d_in, const int* in_sizes, int n_in,
                              void* d_out, int out_size, void* d_ws, size_t ws_size,
                              hipStream_t stream) {
    const int*   x  = (const int*)d_in[0];
    const float* W1 = (const float*)d_in[1];
    const float* b1 = (const float*)d_in[2];
    const float* W2 = (const float*)d_in[3];
    const float* b2 = (const float*)d_in[4];
    const float* W3 = (const float*)d_in[5];
    const float* b3 = (const float*)d_in[6];
    float* out = (float*)d_out;

    const int B = in_sizes[0] / TLEN;   // 65536
    gating_fused<<<B / 64, 256, 0, stream>>>(x, W1, b1, W2, b2, W3, b3, out);
}

// Round 18
// 24.115 us; speedup vs baseline: 1.0221x; 1.0064x over previous
//
#include <hip/hip_runtime.h>

#define TLEN  200
#define H1    128
#define H2    64

typedef __attribute__((ext_vector_type(8))) short bf16x8;
typedef __attribute__((ext_vector_type(4))) float f32x4;

union Frag { unsigned u[4]; bf16x8 v; };

// pack two fp32 into (hi-pair, lo-pair) of bf16 bits: hi = truncate, lo = residual
__device__ __forceinline__ void split2(float v0, float v1, unsigned& hi, unsigned& lo) {
    const unsigned u0 = __float_as_uint(v0), u1 = __float_as_uint(v1);
    hi = __builtin_amdgcn_perm(u1, u0, 0x07060302);          // {u1.hi16, u0.hi16}
    const float d0 = v0 - __uint_as_float(u0 & 0xFFFF0000u);
    const float d1 = v1 - __uint_as_float(u1 & 0xFFFF0000u);
    lo = __builtin_amdgcn_perm(__float_as_uint(d1), __float_as_uint(d0), 0x07060302);
}

// bit-sliced accumulator += a + b (two one-hot u32), 6 planes
__device__ __forceinline__ void csa_add(uint32_t p[6], uint32_t a, uint32_t b) {
    const uint32_t t = a ^ b;
    uint32_t c = (a & b) | (p[0] & t);
    p[0] ^= t;
    uint32_t cn;
    cn = p[1] & c; p[1] ^= c; c = cn;
    cn = p[2] & c; p[2] ^= c; c = cn;
    cn = p[3] & c; p[3] ^= c; c = cn;
    cn = p[4] & c; p[4] ^= c; c = cn;
    p[5] ^= c;
}

// FINAL (R14, session best: 24.14us; reproduced 24.27). 64 samples/block,
// 4 waves, LDS 34816 B. Structure: register bitplane histogram (4 subs/sample,
// CSA one-hot adds, shfl merge) -> bf16 features -> MFMA 16x16x32 MLP with
// hi/lo precision splits -> fused softmax. First x chunk issued before the
// W-convert section (cold-start miss hides under ~250 convert instructions).
// Measured constraint: MLP needs ~84 VGPR (>64-VGPR occupancy cliff) -> fixed
// 4 waves/SIMD; all probes under 64 VGPR (R8, R12, R17) or via kernel splits
// (R10) regressed or failed. Latency-bound plateau at ~60-65% VALU issue.
__global__ __launch_bounds__(256, 4)
void gating_fused(const int* __restrict__ x,
                  const float* __restrict__ W1, const float* __restrict__ b1,
                  const float* __restrict__ W2, const float* __restrict__ b2,
                  const float* __restrict__ W3, const float* __restrict__ b3,
                  float* __restrict__ out)
{
    // overlay plan (34816 B):
    //   phase A (hist -> L1):  feath[64][72] u16 @ 0          (9216 B)
    //   phase B (L1 -> L2):    h1hi[64][136] @ 0, h1lo @ 17408
    //   phase C (L2 -> L3):    h2s[64][67] f32 @ 0            (17152 B)
    //   phase D (L3 -> end):   lbuf stride-5 f32 @ 17408      (5120 B)
    __shared__ __align__(16) unsigned char raw[34816];
    unsigned short (*feath)[72] = (unsigned short (*)[72])raw;
    unsigned short (*h1hi)[136] = (unsigned short (*)[136])raw;
    unsigned short (*h1lo)[136] = (unsigned short (*)[136])(raw + 17408);
    float* h2s  = (float*)raw;
    float* lbuf = (float*)(raw + 17408);      // [(w*64+lane)*5 + e]

    const int tid  = threadIdx.x;
    const int lane = tid & 63;
    const int w    = __builtin_amdgcn_readfirstlane(tid >> 6);
    const int r    = lane & 15;
    const int g    = lane >> 4;

    // ---------- FIRST x chunk in flight before W-convert (cold-start cover) -----
    const int sub   = tid & 3;
    const int s_loc = tid >> 2;
    const long srow = (long)blockIdx.x * 64 + s_loc;
    const int4* xr = (const int4*)(x + srow * TLEN);
    const int nm = (sub < 2) ? 13 : 12;
    int4 cur = xr[sub];                       // +4 VGPR live across convert

    // ---------- W fragments in registers (trunc hi + residual lo bf16) ----------
    Frag w1h[2][2], w1l[2][2], w2h[4], w2l[4];
    #pragma unroll
    for (int n = 0; n < 2; ++n)
        #pragma unroll
        for (int s = 0; s < 2; ++s) {
            const int col = w * 32 + n * 16 + r;
            #pragma unroll
            for (int j = 0; j < 4; ++j) {
                const int k = s * 32 + g * 8 + j * 2;
                const float v0 = (k     < 42) ? W1[k * H1 + col]       : 0.0f;
                const float v1 = (k + 1 < 42) ? W1[(k + 1) * H1 + col] : 0.0f;
                split2(v0, v1, w1h[n][s].u[j], w1l[n][s].u[j]);
            }
        }
    #pragma unroll
    for (int s = 0; s < 4; ++s) {
        const int col = w * 16 + r;
        #pragma unroll
        for (int j = 0; j < 4; ++j) {
            const int k = s * 32 + g * 8 + j * 2;
            split2(W2[k * H2 + col], W2[(k + 1) * H2 + col], w2h[s].u[j], w2l[s].u[j]);
        }
    }
    float b1v[2];
    b1v[0] = b1[w * 32 + r];
    b1v[1] = b1[w * 32 + 16 + r];
    const float b2v = b2[w * 16 + r];

    // ================= histogram: 4 subs/sample, 1-instr one-hot + pair CSA =====
    uint32_t plo[6] = {0,0,0,0,0,0}, phi[6] = {0,0,0,0,0,0};

    for (int m = 0; m < nm; ++m) {
        const int nidx = (m + 1 < nm) ? (sub + 4 * (m + 1)) : sub;
        const int4 nxt = xr[nidx];            // one load in flight during processing
        {   // pad token 0 lands in plane bit 0 -> never extracted (bin 0 skipped)
            const uint64_t oa = 1ull << (cur.x & 63);
            const uint64_t ob = 1ull << (cur.y & 63);
            csa_add(plo, (uint32_t)oa, (uint32_t)ob);
            csa_add(phi, (uint32_t)(oa >> 32), (uint32_t)(ob >> 32));
        }
        {
            const uint64_t oa = 1ull << (cur.z & 63);
            const uint64_t ob = 1ull << (cur.w & 63);
            csa_add(plo, (uint32_t)oa, (uint32_t)ob);
            csa_add(phi, (uint32_t)(oa >> 32), (uint32_t)(ob >> 32));
        }
        cur = nxt;
    }

    // ---- merge planes across the 4 subs (bit-sliced vector adds via shfl) ----
    uint32_t alo[8], ahi[8];
    {
        uint32_t c = 0;
        #pragma unroll
        for (int p = 0; p < 6; ++p) {
            const uint32_t q = __shfl_xor(plo[p], 1);
            const uint32_t t = plo[p] ^ q;
            alo[p] = t ^ c;
            c = (plo[p] & q) | (t & c);
        }
        alo[6] = c;
        c = 0;
        #pragma unroll
        for (int p = 0; p < 6; ++p) {
            const uint32_t q = __shfl_xor(phi[p], 1);
            const uint32_t t = phi[p] ^ q;
            ahi[p] = t ^ c;
            c = (phi[p] & q) | (t & c);
        }
        ahi[6] = c;
        c = 0;
        #pragma unroll
        for (int p = 0; p < 7; ++p) {
            const uint32_t q = __shfl_xor(alo[p], 2);
            const uint32_t t = alo[p] ^ q;
            const uint32_t cn = (alo[p] & q) | (t & c);
            alo[p] = t ^ c;
            c = cn;
        }
        alo[7] = c;
        c = 0;
        #pragma unroll
        for (int p = 0; p < 7; ++p) {
            const uint32_t q = __shfl_xor(ahi[p], 2);
            const uint32_t t = ahi[p] ^ q;
            const uint32_t cn = (ahi[p] & q) | (t & c);
            ahi[p] = t ^ c;
            c = cn;
        }
        ahi[7] = c;
    }

    // ---- extraction: sub s owns a bin slice; bins 1..11 / 12..21 / 22..31 / 32..39
    uint32_t P[8];
    #pragma unroll
    for (int p = 0; p < 8; ++p) P[p] = (sub == 3) ? ahi[p] : alo[p];
    const int nb   = (sub == 0) ? 11 : (sub == 3) ? 8 : 10;
    const int base = (sub == 0) ? 1 : (sub == 1) ? 12 : (sub == 2) ? 22 : 0;
    const int coff = (sub == 3) ? 32 : 0;

    uint32_t tot = 0u, unq = 0u;
    for (int j = 0; j < 11; ++j) {
        if (j < nb) {
            const int sh = base + j;
            uint32_t cnt = 0u;
            #pragma unroll
            for (int p = 0; p < 8; ++p) cnt += ((P[p] >> sh) & 1u) << p;
            tot += cnt;
            unq += (cnt != 0u) ? 1u : 0u;
            feath[s_loc][2 + sh + coff] =
                (unsigned short)(__float_as_uint((float)cnt) >> 16);  // exact int->bf16
        }
    }
    tot += __shfl_xor(tot, 1); tot += __shfl_xor(tot, 2);
    unq += __shfl_xor(unq, 1); unq += __shfl_xor(unq, 2);

    uint32_t* rw = (uint32_t*)&feath[s_loc][0];
    if (sub == 0)
        rw[0] = (__float_as_uint((float)tot) >> 16)
              | ((__float_as_uint((float)unq) >> 16) << 16);      // f[0], f[1]
    if (sub == 1) feath[s_loc][2] = 0;                            // char_freq[0] = 0
    #pragma unroll
    for (int rep = 0; rep < 3; ++rep) {                           // zero k = 42..63
        const int wz = 21 + rep * 4 + sub;
        if (wz <= 31) rw[wz] = 0u;
    }
    __syncthreads();                                              // B1: feat ready

    // ================= layer1: C1[64x128] = feat[64x64] @ W1 ====================
    f32x4 acc1[4][2];
    #pragma unroll
    for (int m = 0; m < 4; ++m)
        #pragma unroll
        for (int n = 0; n < 2; ++n)
            acc1[m][n] = (f32x4){b1v[n], b1v[n], b1v[n], b1v[n]};

    __builtin_amdgcn_s_setprio(1);
    #pragma unroll
    for (int s = 0; s < 2; ++s)
        #pragma unroll
        for (int m = 0; m < 4; ++m) {
            const bf16x8 af = *(const bf16x8*)&feath[m * 16 + r][s * 32 + g * 8];
            #pragma unroll
            for (int n = 0; n < 2; ++n) {
                acc1[m][n] = __builtin_amdgcn_mfma_f32_16x16x32_bf16(af, w1h[n][s].v, acc1[m][n], 0, 0, 0);
                acc1[m][n] = __builtin_amdgcn_mfma_f32_16x16x32_bf16(af, w1l[n][s].v, acc1[m][n], 0, 0, 0);
            }
        }
    __builtin_amdgcn_s_setprio(0);
    __syncthreads();                          // B2: feath reads done (h1 overlays it)

    // relu + trunc hi/lo split -> LDS (C/D: col=lane&15, row=(lane>>4)*4+reg)
    #pragma unroll
    for (int m = 0; m < 4; ++m)
        #pragma unroll
        for (int n = 0; n < 2; ++n)
            #pragma unroll
            for (int j = 0; j < 4; ++j) {
                const float hv = fmaxf(acc1[m][n][j], 0.0f);
                const unsigned ub = __float_as_uint(hv);
                const float d = hv - __uint_as_float(ub & 0xFFFF0000u);
                const int row = m * 16 + g * 4 + j;
                const int col = w * 32 + n * 16 + r;
                h1hi[row][col] = (unsigned short)(ub >> 16);
                h1lo[row][col] = (unsigned short)(__float_as_uint(d) >> 16);
            }
    __syncthreads();                          // B3: h1 ready

    // ================= layer2: C2[64x64] = h1[64x128] @ W2, 3-pass hi/lo ========
    f32x4 acc2[4];
    #pragma unroll
    for (int m = 0; m < 4; ++m) acc2[m] = (f32x4){b2v, b2v, b2v, b2v};

    __builtin_amdgcn_s_setprio(1);
    #pragma unroll
    for (int s = 0; s < 4; ++s)
        #pragma unroll
        for (int m = 0; m < 4; ++m) {
            const int row = m * 16 + r;
            const int kh  = s * 32 + g * 8;
            const bf16x8 ah = *(const bf16x8*)&h1hi[row][kh];
            const bf16x8 al = *(const bf16x8*)&h1lo[row][kh];
            acc2[m] = __builtin_amdgcn_mfma_f32_16x16x32_bf16(ah, w2h[s].v, acc2[m], 0, 0, 0);
            acc2[m] = __builtin_amdgcn_mfma_f32_16x16x32_bf16(al, w2h[s].v, acc2[m], 0, 0, 0);
            acc2[m] = __builtin_amdgcn_mfma_f32_16x16x32_bf16(ah, w2l[s].v, acc2[m], 0, 0, 0);
        }
    __builtin_amdgcn_s_setprio(0);
    __syncthreads();                          // B4: h1 reads done (h2s overlays h1hi)

    // relu(h2) -> fp32 LDS (stride 67 words: conflict-free column gather)
    #pragma unroll
    for (int m = 0; m < 4; ++m)
        #pragma unroll
        for (int j = 0; j < 4; ++j) {
            const int row = m * 16 + g * 4 + j;
            h2s[row * 67 + w * 16 + r] = fmaxf(acc2[m][j], 0.0f);
        }
    // NO barrier (was B5): wave w wrote exactly the h2s columns [w*16, w*16+16)
    // it reads below; within-wave lgkmcnt ordering suffices (R11-verified).

    // ================= layer3 partials: sample per lane, K-split by wave ========
    float lg0 = 0.f, lg1 = 0.f, lg2 = 0.f;
    for (int kk = 0; kk < 16; ++kk) {
        const float hv = h2s[lane * 67 + w * 16 + kk];
        const int wr = (w * 16 + kk) * 3;
        lg0 = fmaf(hv, W3[wr + 0], lg0);
        lg1 = fmaf(hv, W3[wr + 1], lg1);
        lg2 = fmaf(hv, W3[wr + 2], lg2);
    }
    lbuf[(w * 64 + lane) * 5 + 0] = lg0;      // stride 5: gcd(5,32)=1, conflict-free
    lbuf[(w * 64 + lane) * 5 + 1] = lg1;
    lbuf[(w * 64 + lane) * 5 + 2] = lg2;
    __syncthreads();                          // B6: partials ready (cross-wave)

    // ================= reduce, softmax, store ===================================
    float l0 = b3[0], l1 = b3[1], l2 = b3[2];
    #pragma unroll
    for (int wq = 0; wq < 4; ++wq) {
        l0 += lbuf[(wq * 64 + lane) * 5 + 0];
        l1 += lbuf[(wq * 64 + lane) * 5 + 1];
        l2 += lbuf[(wq * 64 + lane) * 5 + 2];
    }
    const float mx  = fmaxf(l0, fmaxf(l1, l2));
    const float e0  = __expf(l0 - mx), e1 = __expf(l1 - mx), e2 = __expf(l2 - mx);
    const float inv = 1.0f / (e0 + e1 + e2);
    if (w < 3) {
        const long gs = (long)blockIdx.x * 64 + lane;
        const float v = (w == 0) ? e0 * inv : (w == 1) ? e1 * inv : e2 * inv;
        out[gs * 3 + w] = v;
    }
}

extern "C" void kernel_launch(void* const* d_in, const int* in_sizes, int n_in,
                              void* d_out, int out_size, void* d_ws, size_t ws_size,
                              hipStream_t stream) {
    const int*   x  = (const int*)d_in[0];
    const float* W1 = (const float*)d_in[1];
    const float* b1 = (const float*)d_in[2];
    const float* W2 = (const float*)d_in[3];
    const float* b2 = (const float*)d_in[4];
    const float* W3 = (const float*)d_in[5];
    const float* b3 = (const float*)d_in[6];
    float* out = (float*)d_out;

    const int B = in_sizes[0] / TLEN;   // 65536
    gating_fused<<<B / 64, 256, 0, stream>>>(x, W1, b1, W2, b2, W3, b3, out);
}